// Round 1
// baseline (168.422 us; speedup 1.0000x reference)
//
#include <hip/hip_runtime.h>
#include <math.h>

#define NCAM 6
#define CH   256
#define HFt  32
#define WFt  88
#define NQ   10000
#define NPT  24   // NCAM * BEV_Z

// ---------------------------------------------------------------------------
// Kernel 1: transpose img_feats (cam, C, H, W) -> (cam, H, W, C)
// so that a bilinear tap reads 256 contiguous floats.
// grid: 6 cams * 32 h * 4 ctiles = 768 blocks, 256 threads
// ---------------------------------------------------------------------------
__global__ __launch_bounds__(256) void k_transpose(const float* __restrict__ img,
                                                   float* __restrict__ outp) {
  int blk = blockIdx.x;
  int ct  = blk & 3;          // c-tile of 64
  int h   = (blk >> 2) & 31;
  int cam = blk >> 7;
  __shared__ float tile[64][89];   // +1 pad: stride 89 (odd) -> no bank conflict
  const float* src = img + (((size_t)cam * CH + ct * 64) * HFt + h) * WFt;
  for (int i = threadIdx.x; i < 64 * WFt; i += 256) {
    int c = i / WFt, w = i - c * WFt;
    tile[c][w] = src[(size_t)c * (HFt * WFt) + w];
  }
  __syncthreads();
  float* dst = outp + ((size_t)(cam * HFt + h) * WFt) * CH + ct * 64;
  for (int i = threadIdx.x; i < WFt * 64; i += 256) {
    int w = i >> 6, c = i & 63;
    dst[(size_t)w * CH + c] = tile[c][w];
  }
}

// ---------------------------------------------------------------------------
// Kernel 2: per-query  logits -> softmax -> project 24 points -> bilinear
// sample+accumulate into A[q, c].  One block (256 threads) per query;
// thread t owns channel t.
// ---------------------------------------------------------------------------
__global__ __launch_bounds__(256) void k_main(const float* __restrict__ query,
                                              const float* __restrict__ featT,
                                              const float* __restrict__ l2i,
                                              const float* __restrict__ aw,
                                              const float* __restrict__ ab,
                                              float* __restrict__ A) {
  const int q = blockIdx.x;
  const int t = threadIdx.x;
  __shared__ float qs[CH];
  __shared__ float Lm[NCAM * 16];
  __shared__ float logits[NPT];
  __shared__ float ew[NPT];
  __shared__ int   poff[NPT][4];
  __shared__ float pw[NPT][4];
  __shared__ int   pval[NPT];

  qs[t] = query[(size_t)q * CH + t];
  if (t < NCAM * 16) Lm[t] = l2i[t];
  __syncthreads();

  // ---- logits: wave w computes logits [6w, 6w+6) ----
  int wave = t >> 6, lane = t & 63;
#pragma unroll
  for (int jj = 0; jj < 6; jj++) {
    int j = wave * 6 + jj;
    float p = 0.f;
#pragma unroll
    for (int k = 0; k < 4; k++) {
      int c = lane + (k << 6);
      p += qs[c] * aw[c * NPT + j];
    }
#pragma unroll
    for (int off = 32; off; off >>= 1) p += __shfl_xor(p, off, 64);
    if (lane == 0) logits[j] = p + ab[j];
  }
  __syncthreads();

  // ---- softmax (24 wide) + point projection, threads 0..23 ----
  if (t < NPT) {
    float m = logits[0];
#pragma unroll
    for (int j = 1; j < NPT; j++) m = fmaxf(m, logits[j]);
    ew[t] = __expf(logits[t] - m);
  }
  __syncthreads();
  if (t < NPT) {
    float s = 0.f;
#pragma unroll
    for (int j = 0; j < NPT; j++) s += ew[j];
    float sw = ew[t] / s;  // softmax weight for (cam = t/4, z = t%4)

    int cam = t >> 2, z = t & 3;
    float X  = (((q % 100) + 0.5f) * 0.01f) * 102.4f - 51.2f;
    float Y  = (((q / 100) + 0.5f) * 0.01f) * 102.4f - 51.2f;
    float Zc = ((z + 0.5f) * 0.25f) * 8.f - 5.f;
    const float* Lr = Lm + cam * 16;
    float cx = Lr[0] * X + Lr[1] * Y + Lr[2]  * Zc + Lr[3];
    float cy = Lr[4] * X + Lr[5] * Y + Lr[6]  * Zc + Lr[7];
    float cd = Lr[8] * X + Lr[9] * Y + Lr[10] * Zc + Lr[11];
    float d  = fmaxf(cd, 1e-5f);
    float gx = (cx / d * (1.f / 87.f) - 0.5f) * 2.f;
    float gy = (cy / d * (1.f / 31.f) - 0.5f) * 2.f;
    bool valid = (cd > 1e-5f) && (gx > -1.f) && (gx < 1.f) && (gy > -1.f) && (gy < 1.f);
    pval[t] = valid ? 1 : 0;

    float x = ((gx + 1.f) * 88.f - 1.f) * 0.5f;
    float y = ((gy + 1.f) * 32.f - 1.f) * 0.5f;
    float x0f = floorf(x), y0f = floorf(y);
    float wx1 = x - x0f, wy1 = y - y0f;
    float wx0 = 1.f - wx1, wy0 = 1.f - wy1;
    bool vx0 = (x0f >= 0.f) && (x0f < 88.f);
    bool vx1 = (x0f + 1.f >= 0.f) && (x0f + 1.f < 88.f);
    bool vy0 = (y0f >= 0.f) && (y0f < 32.f);
    bool vy1 = (y0f + 1.f >= 0.f) && (y0f + 1.f < 32.f);
    int x0 = (int)fminf(fmaxf(x0f, 0.f), 87.f);
    int x1 = (int)fminf(fmaxf(x0f + 1.f, 0.f), 87.f);
    int y0 = (int)fminf(fmaxf(y0f, 0.f), 31.f);
    int y1 = (int)fminf(fmaxf(y0f + 1.f, 0.f), 31.f);
    int cb = cam * (HFt * WFt);
    poff[t][0] = (cb + y0 * WFt + x0) * CH;
    poff[t][1] = (cb + y0 * WFt + x1) * CH;
    poff[t][2] = (cb + y1 * WFt + x0) * CH;
    poff[t][3] = (cb + y1 * WFt + x1) * CH;
    pw[t][0] = sw * wx0 * wy0 * ((vx0 && vy0) ? 1.f : 0.f);
    pw[t][1] = sw * wx1 * wy0 * ((vx1 && vy0) ? 1.f : 0.f);
    pw[t][2] = sw * wx0 * wy1 * ((vx0 && vy1) ? 1.f : 0.f);
    pw[t][3] = sw * wx1 * wy1 * ((vx1 && vy1) ? 1.f : 0.f);
  }
  __syncthreads();

  // ---- accumulate channel t over valid points ----
  float acc = 0.f;
  for (int p = 0; p < NPT; p++) {
    if (!pval[p]) continue;  // block-uniform branch
    float w0 = pw[p][0], w1 = pw[p][1], w2 = pw[p][2], w3 = pw[p][3];
    acc += w0 * featT[poff[p][0] + t];
    acc += w1 * featT[poff[p][1] + t];
    acc += w2 * featT[poff[p][2] + t];
    acc += w3 * featT[poff[p][3] + t];
  }
  A[(size_t)q * CH + t] = acc;
}

// ---------------------------------------------------------------------------
// Kernel 3: out[q, co] = sum_c A[q,c] * out_w[c,co] + out_b[co] + query[q,co]
// 16 queries per block, thread t = output channel co.
// ---------------------------------------------------------------------------
#define QT 16
__global__ __launch_bounds__(256) void k_out(const float* __restrict__ A,
                                             const float* __restrict__ query,
                                             const float* __restrict__ ow,
                                             const float* __restrict__ ob,
                                             float* __restrict__ outp) {
  int qb = blockIdx.x * QT;
  int t  = threadIdx.x;
  __shared__ float As[QT][CH];
  for (int i = t; i < QT * CH; i += 256) {
    int qi = i >> 8, c = i & 255;
    As[qi][c] = A[(size_t)(qb + qi) * CH + c];
  }
  __syncthreads();
  float acc[QT];
#pragma unroll
  for (int i = 0; i < QT; i++) acc[i] = 0.f;
  for (int c4 = 0; c4 < CH; c4 += 4) {
    float w0 = ow[(c4 + 0) * CH + t];
    float w1 = ow[(c4 + 1) * CH + t];
    float w2 = ow[(c4 + 2) * CH + t];
    float w3 = ow[(c4 + 3) * CH + t];
#pragma unroll
    for (int qi = 0; qi < QT; qi++) {
      float4 a = *(const float4*)&As[qi][c4];
      acc[qi] += a.x * w0 + a.y * w1 + a.z * w2 + a.w * w3;
    }
  }
  float b = ob[t];
#pragma unroll
  for (int qi = 0; qi < QT; qi++)
    outp[(size_t)(qb + qi) * CH + t] = acc[qi] + b + query[(size_t)(qb + qi) * CH + t];
}

// ---------------------------------------------------------------------------
extern "C" void kernel_launch(void* const* d_in, const int* in_sizes, int n_in,
                              void* d_out, int out_size, void* d_ws, size_t ws_size,
                              hipStream_t stream) {
  const float* query = (const float*)d_in[0];
  const float* img   = (const float*)d_in[1];
  const float* l2i   = (const float*)d_in[2];
  const float* aw    = (const float*)d_in[3];
  const float* ab    = (const float*)d_in[4];
  const float* ow    = (const float*)d_in[5];
  const float* ob    = (const float*)d_in[6];
  float* outp = (float*)d_out;

  float* featT = (float*)d_ws;                                // 6*32*88*256 f32 = 17.3 MB
  float* A     = featT + (size_t)NCAM * HFt * WFt * CH;       // 10000*256 f32  = 10.2 MB

  k_transpose<<<NCAM * HFt * 4, 256, 0, stream>>>(img, featT);
  k_main<<<NQ, 256, 0, stream>>>(query, featT, l2i, aw, ab, A);
  k_out<<<NQ / QT, 256, 0, stream>>>(A, query, ow, ob, outp);
}

// Round 2
// 73.923 us; speedup vs baseline: 2.2783x; 2.2783x over previous
//
#include <hip/hip_runtime.h>
#include <math.h>

#define NCAM 6
#define CH   256
#define HFt  32
#define WFt  88
#define NQ   10000
#define NPT  24   // NCAM * BEV_Z

// ---------------------------------------------------------------------------
// Kernel 1: transpose img_feats (cam, C, H, W) -> (cam, H, W, C), plus one
// extra block (blockIdx == 768) transposes attn_w (256,24) -> awT (24,256).
// ---------------------------------------------------------------------------
__global__ __launch_bounds__(256) void k_transpose(const float* __restrict__ img,
                                                   const float* __restrict__ aw,
                                                   float* __restrict__ outp,
                                                   float* __restrict__ awT) {
  int blk = blockIdx.x;
  if (blk == NCAM * HFt * 4) {
    int t = threadIdx.x;
#pragma unroll
    for (int j = 0; j < NPT; j++) awT[j * CH + t] = aw[t * NPT + j];
    return;
  }
  int ct  = blk & 3;          // c-tile of 64
  int h   = (blk >> 2) & 31;
  int cam = blk >> 7;
  __shared__ float tile[64][89];   // +1 pad -> no bank conflict
  const float* src = img + (((size_t)cam * CH + ct * 64) * HFt + h) * WFt;
  for (int i = threadIdx.x; i < 64 * WFt; i += 256) {
    int c = i / WFt, w = i - c * WFt;
    tile[c][w] = src[(size_t)c * (HFt * WFt) + w];
  }
  __syncthreads();
  float* dst = outp + ((size_t)(cam * HFt + h) * WFt) * CH + ct * 64;
  for (int i = threadIdx.x; i < WFt * 64; i += 256) {
    int w = i >> 6, c = i & 63;
    dst[(size_t)w * CH + c] = tile[c][w];
  }
}

// ---------------------------------------------------------------------------
// Kernel 2: one WAVE per query. Logits + softmax fully in registers,
// projection on lanes 0..23, ballot-compaction of valid points into a
// per-wave LDS tap list (padded to x8), then a branchless gather with
// 8 outstanding dwordx4 loads per iteration.
// ---------------------------------------------------------------------------
__global__ __launch_bounds__(256) void k_main(const float* __restrict__ query,
                                              const float* __restrict__ featT,
                                              const float* __restrict__ l2i,
                                              const float* __restrict__ awT,
                                              const float* __restrict__ ab,
                                              float* __restrict__ A) {
  const int wv   = threadIdx.x >> 6;
  const int lane = threadIdx.x & 63;
  const int q    = blockIdx.x * 4 + wv;

  __shared__ float Lm[NCAM * 16];
  __shared__ int   offW[4][96];
  __shared__ float wW[4][96];

  if (threadIdx.x < NCAM * 16) Lm[threadIdx.x] = l2i[threadIdx.x];

  // ---- query fragment: channels 4*lane .. 4*lane+3 ----
  float4 q4 = *(const float4*)(query + (size_t)q * CH + 4 * lane);

  // ---- 24 logits, all lanes end up holding every logit ----
  float lg[NPT];
#pragma unroll
  for (int j = 0; j < NPT; j++) {
    float4 a = *(const float4*)(awT + j * CH + 4 * lane);
    float p = q4.x * a.x + q4.y * a.y + q4.z * a.z + q4.w * a.w;
#pragma unroll
    for (int off = 32; off; off >>= 1) p += __shfl_xor(p, off, 64);
    lg[j] = p + ab[j];
  }

  // ---- softmax over 24 (replicated across lanes, static indexing only) ----
  float m = lg[0];
#pragma unroll
  for (int j = 1; j < NPT; j++) m = fmaxf(m, lg[j]);
  float s = 0.f, myE = 0.f;
#pragma unroll
  for (int j = 0; j < NPT; j++) {
    float e = __expf(lg[j] - m);
    s += e;
    if (lane == j) myE = e;
  }
  float sw = myE / s;  // lanes 0..23: softmax weight for point (cam=lane/4, z=lane%4)

  __syncthreads();  // Lm ready (written by waves 0/1, read by all)

  // ---- projection on lanes 0..23 ----
  bool valid = false;
  int o0 = 0, o1 = 0, o2 = 0, o3 = 0;
  float w0 = 0.f, w1 = 0.f, w2 = 0.f, w3 = 0.f;
  if (lane < NPT) {
    int cam = lane >> 2, z = lane & 3;
    float X  = (((q % 100) + 0.5f) * 0.01f) * 102.4f - 51.2f;
    float Y  = (((q / 100) + 0.5f) * 0.01f) * 102.4f - 51.2f;
    float Zc = ((z + 0.5f) * 0.25f) * 8.f - 5.f;
    const float* Lr = Lm + cam * 16;
    float cx = Lr[0] * X + Lr[1] * Y + Lr[2]  * Zc + Lr[3];
    float cy = Lr[4] * X + Lr[5] * Y + Lr[6]  * Zc + Lr[7];
    float cd = Lr[8] * X + Lr[9] * Y + Lr[10] * Zc + Lr[11];
    float d  = fmaxf(cd, 1e-5f);
    float gx = (cx / d * (1.f / 87.f) - 0.5f) * 2.f;
    float gy = (cy / d * (1.f / 31.f) - 0.5f) * 2.f;
    valid = (cd > 1e-5f) && (gx > -1.f) && (gx < 1.f) && (gy > -1.f) && (gy < 1.f);

    float x = ((gx + 1.f) * 88.f - 1.f) * 0.5f;
    float y = ((gy + 1.f) * 32.f - 1.f) * 0.5f;
    float x0f = floorf(x), y0f = floorf(y);
    float wx1 = x - x0f, wy1 = y - y0f;
    float wx0 = 1.f - wx1, wy0 = 1.f - wy1;
    bool vx0 = (x0f >= 0.f) && (x0f < 88.f);
    bool vx1 = (x0f + 1.f >= 0.f) && (x0f + 1.f < 88.f);
    bool vy0 = (y0f >= 0.f) && (y0f < 32.f);
    bool vy1 = (y0f + 1.f >= 0.f) && (y0f + 1.f < 32.f);
    int x0 = (int)fminf(fmaxf(x0f, 0.f), 87.f);
    int x1 = (int)fminf(fmaxf(x0f + 1.f, 0.f), 87.f);
    int y0 = (int)fminf(fmaxf(y0f, 0.f), 31.f);
    int y1 = (int)fminf(fmaxf(y0f + 1.f, 0.f), 31.f);
    int cb = cam * (HFt * WFt);
    o0 = (cb + y0 * WFt + x0) * CH;
    o1 = (cb + y0 * WFt + x1) * CH;
    o2 = (cb + y1 * WFt + x0) * CH;
    o3 = (cb + y1 * WFt + x1) * CH;
    w0 = sw * wx0 * wy0 * ((vx0 && vy0) ? 1.f : 0.f);
    w1 = sw * wx1 * wy0 * ((vx1 && vy0) ? 1.f : 0.f);
    w2 = sw * wx0 * wy1 * ((vx0 && vy1) ? 1.f : 0.f);
    w3 = sw * wx1 * wy1 * ((vx1 && vy1) ? 1.f : 0.f);
  }

  // ---- ballot-compact valid points into per-wave LDS tap list ----
  unsigned long long vm = __ballot(valid);
  int nvalid = __popcll(vm);
  int pos = __popcll(vm & ((1ull << lane) - 1ull));
  if (valid) {
    int b = 4 * pos;
    offW[wv][b + 0] = o0; wW[wv][b + 0] = w0;
    offW[wv][b + 1] = o1; wW[wv][b + 1] = w1;
    offW[wv][b + 2] = o2; wW[wv][b + 2] = w2;
    offW[wv][b + 3] = o3; wW[wv][b + 3] = w3;
  }
  int nt  = 4 * nvalid;
  int ntp = (nt + 7) & ~7;
  if (lane < ntp - nt) { offW[wv][nt + lane] = 0; wW[wv][nt + lane] = 0.f; }

  // ---- branchless gather: 8 taps / iteration, dual accumulators ----
  float4 acc0 = {0.f, 0.f, 0.f, 0.f}, acc1 = {0.f, 0.f, 0.f, 0.f};
  const float* fb = featT + 4 * lane;
  for (int i = 0; i < ntp; i += 8) {
    int   a0 = offW[wv][i + 0], a1 = offW[wv][i + 1], a2 = offW[wv][i + 2], a3 = offW[wv][i + 3];
    int   a4 = offW[wv][i + 4], a5 = offW[wv][i + 5], a6 = offW[wv][i + 6], a7 = offW[wv][i + 7];
    float b0 = wW[wv][i + 0], b1 = wW[wv][i + 1], b2 = wW[wv][i + 2], b3 = wW[wv][i + 3];
    float b4 = wW[wv][i + 4], b5 = wW[wv][i + 5], b6 = wW[wv][i + 6], b7 = wW[wv][i + 7];
    float4 v0 = *(const float4*)(fb + a0);
    float4 v1 = *(const float4*)(fb + a1);
    float4 v2 = *(const float4*)(fb + a2);
    float4 v3 = *(const float4*)(fb + a3);
    float4 v4 = *(const float4*)(fb + a4);
    float4 v5 = *(const float4*)(fb + a5);
    float4 v6 = *(const float4*)(fb + a6);
    float4 v7 = *(const float4*)(fb + a7);
    acc0.x = fmaf(b0, v0.x, acc0.x); acc0.y = fmaf(b0, v0.y, acc0.y);
    acc0.z = fmaf(b0, v0.z, acc0.z); acc0.w = fmaf(b0, v0.w, acc0.w);
    acc1.x = fmaf(b1, v1.x, acc1.x); acc1.y = fmaf(b1, v1.y, acc1.y);
    acc1.z = fmaf(b1, v1.z, acc1.z); acc1.w = fmaf(b1, v1.w, acc1.w);
    acc0.x = fmaf(b2, v2.x, acc0.x); acc0.y = fmaf(b2, v2.y, acc0.y);
    acc0.z = fmaf(b2, v2.z, acc0.z); acc0.w = fmaf(b2, v2.w, acc0.w);
    acc1.x = fmaf(b3, v3.x, acc1.x); acc1.y = fmaf(b3, v3.y, acc1.y);
    acc1.z = fmaf(b3, v3.z, acc1.z); acc1.w = fmaf(b3, v3.w, acc1.w);
    acc0.x = fmaf(b4, v4.x, acc0.x); acc0.y = fmaf(b4, v4.y, acc0.y);
    acc0.z = fmaf(b4, v4.z, acc0.z); acc0.w = fmaf(b4, v4.w, acc0.w);
    acc1.x = fmaf(b5, v5.x, acc1.x); acc1.y = fmaf(b5, v5.y, acc1.y);
    acc1.z = fmaf(b5, v5.z, acc1.z); acc1.w = fmaf(b5, v5.w, acc1.w);
    acc0.x = fmaf(b6, v6.x, acc0.x); acc0.y = fmaf(b6, v6.y, acc0.y);
    acc0.z = fmaf(b6, v6.z, acc0.z); acc0.w = fmaf(b6, v6.w, acc0.w);
    acc1.x = fmaf(b7, v7.x, acc1.x); acc1.y = fmaf(b7, v7.y, acc1.y);
    acc1.z = fmaf(b7, v7.z, acc1.z); acc1.w = fmaf(b7, v7.w, acc1.w);
  }
  float4 r;
  r.x = acc0.x + acc1.x; r.y = acc0.y + acc1.y;
  r.z = acc0.z + acc1.z; r.w = acc0.w + acc1.w;
  *(float4*)(A + (size_t)q * CH + 4 * lane) = r;
}

// ---------------------------------------------------------------------------
// Kernel 3: out[q, co] = sum_c A[q,c] * out_w[c,co] + out_b[co] + query[q,co]
// ---------------------------------------------------------------------------
#define QT 16
__global__ __launch_bounds__(256) void k_out(const float* __restrict__ A,
                                             const float* __restrict__ query,
                                             const float* __restrict__ ow,
                                             const float* __restrict__ ob,
                                             float* __restrict__ outp) {
  int qb = blockIdx.x * QT;
  int t  = threadIdx.x;
  __shared__ float As[QT][CH];
  for (int i = t; i < QT * CH; i += 256) {
    int qi = i >> 8, c = i & 255;
    As[qi][c] = A[(size_t)(qb + qi) * CH + c];
  }
  __syncthreads();
  float acc[QT];
#pragma unroll
  for (int i = 0; i < QT; i++) acc[i] = 0.f;
  for (int c4 = 0; c4 < CH; c4 += 4) {
    float w0 = ow[(c4 + 0) * CH + t];
    float w1 = ow[(c4 + 1) * CH + t];
    float w2 = ow[(c4 + 2) * CH + t];
    float w3 = ow[(c4 + 3) * CH + t];
#pragma unroll
    for (int qi = 0; qi < QT; qi++) {
      float4 a = *(const float4*)&As[qi][c4];
      acc[qi] += a.x * w0 + a.y * w1 + a.z * w2 + a.w * w3;
    }
  }
  float b = ob[t];
#pragma unroll
  for (int qi = 0; qi < QT; qi++)
    outp[(size_t)(qb + qi) * CH + t] = acc[qi] + b + query[(size_t)(qb + qi) * CH + t];
}

// ---------------------------------------------------------------------------
extern "C" void kernel_launch(void* const* d_in, const int* in_sizes, int n_in,
                              void* d_out, int out_size, void* d_ws, size_t ws_size,
                              hipStream_t stream) {
  const float* query = (const float*)d_in[0];
  const float* img   = (const float*)d_in[1];
  const float* l2i   = (const float*)d_in[2];
  const float* aw    = (const float*)d_in[3];
  const float* ab    = (const float*)d_in[4];
  const float* ow    = (const float*)d_in[5];
  const float* ob    = (const float*)d_in[6];
  float* outp = (float*)d_out;

  float* featT = (float*)d_ws;                                // 17.3 MB
  float* A     = featT + (size_t)NCAM * HFt * WFt * CH;       // 10.2 MB
  float* awT   = A + (size_t)NQ * CH;                         // 24 KB

  k_transpose<<<NCAM * HFt * 4 + 1, 256, 0, stream>>>(img, aw, featT, awT);
  k_main<<<NQ / 4, 256, 0, stream>>>(query, featT, l2i, awT, ab, A);
  k_out<<<NQ / QT, 256, 0, stream>>>(A, query, ow, ob, outp);
}

// Round 3
// 42.655 us; speedup vs baseline: 3.9485x; 1.7331x over previous
//
#include <hip/hip_runtime.h>
#include <math.h>

#define NCAM 6
#define CH   256
#define HFt  32
#define WFt  88
#define NQ   10000
#define NPT  24   // NCAM * BEV_Z

typedef __attribute__((ext_vector_type(8))) short short8;
typedef __attribute__((ext_vector_type(4))) float f32x4;

__device__ __forceinline__ unsigned short f2bf(float x) {
  unsigned int u = __float_as_uint(x);
  u += 0x7FFFu + ((u >> 16) & 1u);   // round-to-nearest-even
  return (unsigned short)(u >> 16);
}

// ---------------------------------------------------------------------------
// Kernel 1: blocks 0..767: transpose img_feats (cam,C,H,W) -> (cam,H,W,C).
// block 768: transpose attn_w (256,24) -> awT (24,256).
// blocks 769..800: pack out_w into per-lane MFMA B-fragment order (bf16).
//   W_sw index = ((chunk*8 + kk)*2 + f)*64 + lane, 8 bf16 (16B) per entry:
//   n = 32*chunk + 16*f + (lane&15), kb = 32*kk + 4*(lane>>4)
//   elems 0..3: ow[kb+e][n]; elems 4..7: ow[kb+16+e][n]
// ---------------------------------------------------------------------------
__global__ __launch_bounds__(256) void k_transpose(const float* __restrict__ img,
                                                   const float* __restrict__ aw,
                                                   const float* __restrict__ ow,
                                                   float* __restrict__ outp,
                                                   float* __restrict__ awT,
                                                   unsigned short* __restrict__ Wsw) {
  int blk = blockIdx.x;
  if (blk >= NCAM * HFt * 4 + 1) {  // ---- W_sw pack ----
    int gtid = (blk - (NCAM * HFt * 4 + 1)) * 256 + threadIdx.x;  // [0, 8192)
    int l  = gtid & 63;
    int f  = (gtid >> 6) & 1;
    int kk = (gtid >> 7) & 7;
    int c  = gtid >> 10;
    int n  = 32 * c + 16 * f + (l & 15);
    int kb = 32 * kk + 4 * (l >> 4);
    unsigned int u0 = f2bf(ow[(kb + 0) * CH + n]) | ((unsigned int)f2bf(ow[(kb + 1) * CH + n]) << 16);
    unsigned int u1 = f2bf(ow[(kb + 2) * CH + n]) | ((unsigned int)f2bf(ow[(kb + 3) * CH + n]) << 16);
    unsigned int u2 = f2bf(ow[(kb + 16) * CH + n]) | ((unsigned int)f2bf(ow[(kb + 17) * CH + n]) << 16);
    unsigned int u3 = f2bf(ow[(kb + 18) * CH + n]) | ((unsigned int)f2bf(ow[(kb + 19) * CH + n]) << 16);
    ((uint4*)Wsw)[gtid] = make_uint4(u0, u1, u2, u3);
    return;
  }
  if (blk == NCAM * HFt * 4) {      // ---- awT ----
    int t = threadIdx.x;
#pragma unroll
    for (int j = 0; j < NPT; j++) awT[j * CH + t] = aw[t * NPT + j];
    return;
  }
  int ct  = blk & 3;
  int h   = (blk >> 2) & 31;
  int cam = blk >> 7;
  __shared__ float tile[64][89];
  const float* src = img + (((size_t)cam * CH + ct * 64) * HFt + h) * WFt;
  for (int i = threadIdx.x; i < 64 * WFt; i += 256) {
    int c = i / WFt, w = i - c * WFt;
    tile[c][w] = src[(size_t)c * (HFt * WFt) + w];
  }
  __syncthreads();
  float* dst = outp + ((size_t)(cam * HFt + h) * WFt) * CH + ct * 64;
  for (int i = threadIdx.x; i < WFt * 64; i += 256) {
    int w = i >> 6, c = i & 63;
    dst[(size_t)w * CH + c] = tile[c][w];
  }
}

// ---------------------------------------------------------------------------
// Kernel 2: one WAVE per query (unchanged from R2 except bf16 A output).
// ---------------------------------------------------------------------------
__global__ __launch_bounds__(256) void k_main(const float* __restrict__ query,
                                              const float* __restrict__ featT,
                                              const float* __restrict__ l2i,
                                              const float* __restrict__ awT,
                                              const float* __restrict__ ab,
                                              unsigned short* __restrict__ A) {
  const int wv   = threadIdx.x >> 6;
  const int lane = threadIdx.x & 63;
  const int q    = blockIdx.x * 4 + wv;

  __shared__ float Lm[NCAM * 16];
  __shared__ int   offW[4][96];
  __shared__ float wW[4][96];

  if (threadIdx.x < NCAM * 16) Lm[threadIdx.x] = l2i[threadIdx.x];

  float4 q4 = *(const float4*)(query + (size_t)q * CH + 4 * lane);

  float lg[NPT];
#pragma unroll
  for (int j = 0; j < NPT; j++) {
    float4 a = *(const float4*)(awT + j * CH + 4 * lane);
    float p = q4.x * a.x + q4.y * a.y + q4.z * a.z + q4.w * a.w;
#pragma unroll
    for (int off = 32; off; off >>= 1) p += __shfl_xor(p, off, 64);
    lg[j] = p + ab[j];
  }

  float m = lg[0];
#pragma unroll
  for (int j = 1; j < NPT; j++) m = fmaxf(m, lg[j]);
  float s = 0.f, myE = 0.f;
#pragma unroll
  for (int j = 0; j < NPT; j++) {
    float e = __expf(lg[j] - m);
    s += e;
    if (lane == j) myE = e;
  }
  float sw = myE / s;

  __syncthreads();  // Lm ready

  bool valid = false;
  int o0 = 0, o1 = 0, o2 = 0, o3 = 0;
  float w0 = 0.f, w1 = 0.f, w2 = 0.f, w3 = 0.f;
  if (lane < NPT) {
    int cam = lane >> 2, z = lane & 3;
    float X  = (((q % 100) + 0.5f) * 0.01f) * 102.4f - 51.2f;
    float Y  = (((q / 100) + 0.5f) * 0.01f) * 102.4f - 51.2f;
    float Zc = ((z + 0.5f) * 0.25f) * 8.f - 5.f;
    const float* Lr = Lm + cam * 16;
    float cx = Lr[0] * X + Lr[1] * Y + Lr[2]  * Zc + Lr[3];
    float cy = Lr[4] * X + Lr[5] * Y + Lr[6]  * Zc + Lr[7];
    float cd = Lr[8] * X + Lr[9] * Y + Lr[10] * Zc + Lr[11];
    float d  = fmaxf(cd, 1e-5f);
    float gx = (cx / d * (1.f / 87.f) - 0.5f) * 2.f;
    float gy = (cy / d * (1.f / 31.f) - 0.5f) * 2.f;
    valid = (cd > 1e-5f) && (gx > -1.f) && (gx < 1.f) && (gy > -1.f) && (gy < 1.f);

    float x = ((gx + 1.f) * 88.f - 1.f) * 0.5f;
    float y = ((gy + 1.f) * 32.f - 1.f) * 0.5f;
    float x0f = floorf(x), y0f = floorf(y);
    float wx1 = x - x0f, wy1 = y - y0f;
    float wx0 = 1.f - wx1, wy0 = 1.f - wy1;
    bool vx0 = (x0f >= 0.f) && (x0f < 88.f);
    bool vx1 = (x0f + 1.f >= 0.f) && (x0f + 1.f < 88.f);
    bool vy0 = (y0f >= 0.f) && (y0f < 32.f);
    bool vy1 = (y0f + 1.f >= 0.f) && (y0f + 1.f < 32.f);
    int x0 = (int)fminf(fmaxf(x0f, 0.f), 87.f);
    int x1 = (int)fminf(fmaxf(x0f + 1.f, 0.f), 87.f);
    int y0 = (int)fminf(fmaxf(y0f, 0.f), 31.f);
    int y1 = (int)fminf(fmaxf(y0f + 1.f, 0.f), 31.f);
    int cb = cam * (HFt * WFt);
    o0 = (cb + y0 * WFt + x0) * CH;
    o1 = (cb + y0 * WFt + x1) * CH;
    o2 = (cb + y1 * WFt + x0) * CH;
    o3 = (cb + y1 * WFt + x1) * CH;
    w0 = sw * wx0 * wy0 * ((vx0 && vy0) ? 1.f : 0.f);
    w1 = sw * wx1 * wy0 * ((vx1 && vy0) ? 1.f : 0.f);
    w2 = sw * wx0 * wy1 * ((vx0 && vy1) ? 1.f : 0.f);
    w3 = sw * wx1 * wy1 * ((vx1 && vy1) ? 1.f : 0.f);
  }

  unsigned long long vm = __ballot(valid);
  int nvalid = __popcll(vm);
  int pos = __popcll(vm & ((1ull << lane) - 1ull));
  if (valid) {
    int b = 4 * pos;
    offW[wv][b + 0] = o0; wW[wv][b + 0] = w0;
    offW[wv][b + 1] = o1; wW[wv][b + 1] = w1;
    offW[wv][b + 2] = o2; wW[wv][b + 2] = w2;
    offW[wv][b + 3] = o3; wW[wv][b + 3] = w3;
  }
  int nt  = 4 * nvalid;
  int ntp = (nt + 7) & ~7;
  if (lane < ntp - nt) { offW[wv][nt + lane] = 0; wW[wv][nt + lane] = 0.f; }

  float4 acc0 = {0.f, 0.f, 0.f, 0.f}, acc1 = {0.f, 0.f, 0.f, 0.f};
  const float* fb = featT + 4 * lane;
  for (int i = 0; i < ntp; i += 8) {
    int   a0 = offW[wv][i + 0], a1 = offW[wv][i + 1], a2 = offW[wv][i + 2], a3 = offW[wv][i + 3];
    int   a4 = offW[wv][i + 4], a5 = offW[wv][i + 5], a6 = offW[wv][i + 6], a7 = offW[wv][i + 7];
    float b0 = wW[wv][i + 0], b1 = wW[wv][i + 1], b2 = wW[wv][i + 2], b3 = wW[wv][i + 3];
    float b4 = wW[wv][i + 4], b5 = wW[wv][i + 5], b6 = wW[wv][i + 6], b7 = wW[wv][i + 7];
    float4 v0 = *(const float4*)(fb + a0);
    float4 v1 = *(const float4*)(fb + a1);
    float4 v2 = *(const float4*)(fb + a2);
    float4 v3 = *(const float4*)(fb + a3);
    float4 v4 = *(const float4*)(fb + a4);
    float4 v5 = *(const float4*)(fb + a5);
    float4 v6 = *(const float4*)(fb + a6);
    float4 v7 = *(const float4*)(fb + a7);
    acc0.x = fmaf(b0, v0.x, acc0.x); acc0.y = fmaf(b0, v0.y, acc0.y);
    acc0.z = fmaf(b0, v0.z, acc0.z); acc0.w = fmaf(b0, v0.w, acc0.w);
    acc1.x = fmaf(b1, v1.x, acc1.x); acc1.y = fmaf(b1, v1.y, acc1.y);
    acc1.z = fmaf(b1, v1.z, acc1.z); acc1.w = fmaf(b1, v1.w, acc1.w);
    acc0.x = fmaf(b2, v2.x, acc0.x); acc0.y = fmaf(b2, v2.y, acc0.y);
    acc0.z = fmaf(b2, v2.z, acc0.z); acc0.w = fmaf(b2, v2.w, acc0.w);
    acc1.x = fmaf(b3, v3.x, acc1.x); acc1.y = fmaf(b3, v3.y, acc1.y);
    acc1.z = fmaf(b3, v3.z, acc1.z); acc1.w = fmaf(b3, v3.w, acc1.w);
    acc0.x = fmaf(b4, v4.x, acc0.x); acc0.y = fmaf(b4, v4.y, acc0.y);
    acc0.z = fmaf(b4, v4.z, acc0.z); acc0.w = fmaf(b4, v4.w, acc0.w);
    acc1.x = fmaf(b5, v5.x, acc1.x); acc1.y = fmaf(b5, v5.y, acc1.y);
    acc1.z = fmaf(b5, v5.z, acc1.z); acc1.w = fmaf(b5, v5.w, acc1.w);
    acc0.x = fmaf(b6, v6.x, acc0.x); acc0.y = fmaf(b6, v6.y, acc0.y);
    acc0.z = fmaf(b6, v6.z, acc0.z); acc0.w = fmaf(b6, v6.w, acc0.w);
    acc1.x = fmaf(b7, v7.x, acc1.x); acc1.y = fmaf(b7, v7.y, acc1.y);
    acc1.z = fmaf(b7, v7.z, acc1.z); acc1.w = fmaf(b7, v7.w, acc1.w);
  }
  float4 r;
  r.x = acc0.x + acc1.x; r.y = acc0.y + acc1.y;
  r.z = acc0.z + acc1.z; r.w = acc0.w + acc1.w;
  ushort4 st;
  st.x = f2bf(r.x); st.y = f2bf(r.y); st.z = f2bf(r.z); st.w = f2bf(r.w);
  *(ushort4*)(A + (size_t)q * CH + 4 * lane) = st;
}

// ---------------------------------------------------------------------------
// Kernel 3 (MFMA): out[m,n] = sum_k A[m,k]*W[k,n] + ob[n] + query[m,n]
// block = 16 rows x 128 cols; 4 waves, each wave 2 N-frags; K=256 = 8 steps.
// grid = 625 * 2 = 1250 (exact fit, no guards).
// ---------------------------------------------------------------------------
#define ASP 264   // padded LDS row stride (bf16 elems): bank-balanced b64 reads
__global__ __launch_bounds__(256) void k_out_mfma(const unsigned short* __restrict__ A,
                                                  const float* __restrict__ query,
                                                  const unsigned short* __restrict__ Wsw,
                                                  const float* __restrict__ ob,
                                                  float* __restrict__ outp) {
  const int blk = blockIdx.x;
  const int mtile = blk >> 1, nhalf = blk & 1;
  const int m0 = mtile * 16;
  const int t = threadIdx.x, wv = t >> 6, l = t & 63;
  const int row = l & 15, grp = l >> 4;

  __shared__ unsigned short As[16 * ASP];

  // ---- stage A tile (16 x 256 bf16 = 8 KB), padded rows ----
  {
    const uint4* src = (const uint4*)(A + (size_t)m0 * CH);  // 512 granules of 8 bf16
    uint4 v0 = src[t];
    uint4 v1 = src[t + 256];
    int r0 = t >> 5, c0 = t & 31;
    int g1 = t + 256; int r1 = g1 >> 5, c1 = g1 & 31;
    *(uint4*)(&As[r0 * ASP + c0 * 8]) = v0;
    *(uint4*)(&As[r1 * ASP + c1 * 8]) = v1;
  }
  __syncthreads();

  // ---- preload all 8 A-fragments from LDS ----
  short8 af[8];
  {
    const unsigned short* ap = &As[row * ASP + 4 * grp];
#pragma unroll
    for (int kk = 0; kk < 8; kk++) {
      uint2 lo = *(const uint2*)(ap + kk * 32);
      uint2 hi = *(const uint2*)(ap + kk * 32 + 16);
      union { uint4 u; short8 s; } x;
      x.u.x = lo.x; x.u.y = lo.y; x.u.z = hi.x; x.u.w = hi.y;
      af[kk] = x.s;
    }
  }

  // ---- K loop: coalesced pre-swizzled W loads + MFMA ----
  const int chunk = nhalf * 4 + wv;   // 32-col chunk id
  const uint4* wp = (const uint4*)Wsw;
  f32x4 acc0 = {0.f, 0.f, 0.f, 0.f}, acc1 = {0.f, 0.f, 0.f, 0.f};
#pragma unroll
  for (int kk = 0; kk < 8; kk++) {
    uint4 w0 = wp[((chunk * 8 + kk) * 2 + 0) * 64 + l];
    uint4 w1 = wp[((chunk * 8 + kk) * 2 + 1) * 64 + l];
    union { uint4 u; short8 s; } b0, b1;
    b0.u = w0; b1.u = w1;
    acc0 = __builtin_amdgcn_mfma_f32_16x16x32_bf16(af[kk], b0.s, acc0, 0, 0, 0);
    acc1 = __builtin_amdgcn_mfma_f32_16x16x32_bf16(af[kk], b1.s, acc1, 0, 0, 0);
  }

  // ---- epilogue: bias + residual, C/D map: n = n0+(l&15), m = m0+4*grp+r ----
  const int nbase = nhalf * 128 + wv * 32;
#pragma unroll
  for (int f = 0; f < 2; f++) {
    f32x4 ac = (f == 0) ? acc0 : acc1;
    int n = nbase + 16 * f + row;
    float bias = ob[n];
#pragma unroll
    for (int r = 0; r < 4; r++) {
      int m = m0 + 4 * grp + r;
      size_t idx = (size_t)m * CH + n;
      outp[idx] = ac[r] + bias + query[idx];
    }
  }
}

// ---------------------------------------------------------------------------
extern "C" void kernel_launch(void* const* d_in, const int* in_sizes, int n_in,
                              void* d_out, int out_size, void* d_ws, size_t ws_size,
                              hipStream_t stream) {
  const float* query = (const float*)d_in[0];
  const float* img   = (const float*)d_in[1];
  const float* l2i   = (const float*)d_in[2];
  const float* aw    = (const float*)d_in[3];
  const float* ab    = (const float*)d_in[4];
  const float* ow    = (const float*)d_in[5];
  const float* ob    = (const float*)d_in[6];
  float* outp = (float*)d_out;

  char* ws = (char*)d_ws;
  float*          featT = (float*)ws;                         // 17,301,504 B
  unsigned short* Abf   = (unsigned short*)(ws + 17301504);   //  5,120,000 B
  float*          awT   = (float*)(ws + 22421504);            //     24,576 B
  unsigned short* Wsw   = (unsigned short*)(ws + 22446080);   //    131,072 B

  k_transpose<<<NCAM * HFt * 4 + 1 + 32, 256, 0, stream>>>(img, aw, ow, featT, awT, Wsw);
  k_main<<<NQ / 4, 256, 0, stream>>>(query, featT, l2i, awT, ab, Abf);
  k_out_mfma<<<(NQ / 16) * 2, 256, 0, stream>>>(Abf, query, Wsw, ob, outp);
}

// Round 4
// 35.486 us; speedup vs baseline: 4.7461x; 1.2020x over previous
//
#include <hip/hip_runtime.h>
#include <math.h>

#define NCAM 6
#define CH   256
#define HFt  32
#define WFt  88
#define NQ   10000
#define NPT  24   // NCAM * BEV_Z

typedef __attribute__((ext_vector_type(8))) short short8;
typedef __attribute__((ext_vector_type(4))) float f32x4;

__device__ __forceinline__ unsigned short f2bf(float x) {
  unsigned int u = __float_as_uint(x);
  u += 0x7FFFu + ((u >> 16) & 1u);   // round-to-nearest-even
  return (unsigned short)(u >> 16);
}
__device__ __forceinline__ float bf2f(unsigned short b) {
  return __uint_as_float(((unsigned int)b) << 16);
}

#define TRBLKS  (NCAM * HFt * 4)        // 768 transpose blocks
#define WSWBLKS 32                      // out_w pack blocks
#define LOGITS0 (TRBLKS + WSWBLKS)      // 800
#define NLB     157                     // ceil(10000 / 64) logits blocks

// ---------------------------------------------------------------------------
// k_prep: blocks 0..767   : img_feats (cam,C,H,W) f32 -> featT (cam,H,W,C) bf16
//         blocks 768..799 : out_w -> Wsw per-lane MFMA B-fragment pack (bf16)
//         blocks 800..956 : logits GEMM (query @ attn_w + attn_b) via MFMA
//                           + row softmax -> Wgt[q][24] f32
// ---------------------------------------------------------------------------
__global__ __launch_bounds__(256) void k_prep(const float* __restrict__ img,
                                              const float* __restrict__ query,
                                              const float* __restrict__ aw,
                                              const float* __restrict__ ab,
                                              const float* __restrict__ ow,
                                              unsigned short* __restrict__ featT,
                                              unsigned short* __restrict__ Wsw,
                                              float* __restrict__ Wgt) {
  __shared__ __align__(16) char smem[50176];
  const int blk = blockIdx.x;
  const int tid = threadIdx.x;

  if (blk < TRBLKS) {  // ---- transpose to bf16 ----
    float (*tile)[89] = (float(*)[89])smem;   // 64 x 89 f32, padded
    int ct = blk & 3, h = (blk >> 2) & 31, cam = blk >> 7;
    const float* src = img + (((size_t)cam * CH + ct * 64) * HFt + h) * WFt;
    for (int i = tid; i < 64 * WFt; i += 256) {
      int c = i / WFt, w = i - c * WFt;
      tile[c][w] = src[(size_t)c * (HFt * WFt) + w];
    }
    __syncthreads();
    unsigned short* dst = featT + ((size_t)(cam * HFt + h) * WFt) * CH + ct * 64;
    for (int i = tid; i < WFt * 32; i += 256) {
      int w = i >> 5, cp = i & 31;
      unsigned int u = (unsigned int)f2bf(tile[2 * cp][w]) |
                       ((unsigned int)f2bf(tile[2 * cp + 1][w]) << 16);
      *(unsigned int*)(dst + (size_t)w * CH + 2 * cp) = u;
    }
    return;
  }

  if (blk < LOGITS0) {  // ---- Wsw pack (identical mapping to R3, proven) ----
    int gtid = (blk - TRBLKS) * 256 + tid;  // [0, 8192)
    int l  = gtid & 63;
    int f  = (gtid >> 6) & 1;
    int kk = (gtid >> 7) & 7;
    int c  = gtid >> 10;
    int n  = 32 * c + 16 * f + (l & 15);
    int kb = 32 * kk + 4 * (l >> 4);
    unsigned int u0 = f2bf(ow[(kb + 0) * CH + n])  | ((unsigned int)f2bf(ow[(kb + 1) * CH + n])  << 16);
    unsigned int u1 = f2bf(ow[(kb + 2) * CH + n])  | ((unsigned int)f2bf(ow[(kb + 3) * CH + n])  << 16);
    unsigned int u2 = f2bf(ow[(kb + 16) * CH + n]) | ((unsigned int)f2bf(ow[(kb + 17) * CH + n]) << 16);
    unsigned int u3 = f2bf(ow[(kb + 18) * CH + n]) | ((unsigned int)f2bf(ow[(kb + 19) * CH + n]) << 16);
    ((uint4*)Wsw)[gtid] = make_uint4(u0, u1, u2, u3);
    return;
  }

  // ---- logits block: 64 queries, 4 waves x 16 queries each ----
  const int q0 = (blk - LOGITS0) * 64;
  uint4*          awB = (uint4*)smem;                       // 1024 uint4 = 16 KB
  unsigned short* As  = (unsigned short*)(smem + 16384);    // 64 x 264 bf16 = 33.8 KB

  // stage query tile (f32 -> bf16), padded row stride 264
  for (int i = tid; i < 64 * 64; i += 256) {
    int row = i >> 6, g = i & 63;
    int qq = q0 + row;
    float4 v = (qq < NQ) ? *(const float4*)(query + (size_t)qq * CH + 4 * g)
                         : make_float4(0.f, 0.f, 0.f, 0.f);
    ushort4 s4;
    s4.x = f2bf(v.x); s4.y = f2bf(v.y); s4.z = f2bf(v.z); s4.w = f2bf(v.w);
    *(ushort4*)(As + row * 264 + 4 * g) = s4;
  }
  // pack attn_w B-fragments (cols >= 24 zero), same k-slot map as A reads
  for (int e = tid; e < 1024; e += 256) {
    int l = e & 63, f = (e >> 6) & 1, kk = e >> 7;
    int n = 16 * f + (l & 15);
    int kb = 32 * kk + 4 * (l >> 4);
    uint4 u = make_uint4(0u, 0u, 0u, 0u);
    if (n < NPT) {
      u.x = f2bf(aw[(kb + 0) * NPT + n])  | ((unsigned int)f2bf(aw[(kb + 1) * NPT + n])  << 16);
      u.y = f2bf(aw[(kb + 2) * NPT + n])  | ((unsigned int)f2bf(aw[(kb + 3) * NPT + n])  << 16);
      u.z = f2bf(aw[(kb + 16) * NPT + n]) | ((unsigned int)f2bf(aw[(kb + 17) * NPT + n]) << 16);
      u.w = f2bf(aw[(kb + 18) * NPT + n]) | ((unsigned int)f2bf(aw[(kb + 19) * NPT + n]) << 16);
    }
    awB[e] = u;
  }
  __syncthreads();

  const int wv = tid >> 6, l = tid & 63;
  const int col = l & 15, grp = l >> 4;

  short8 af[8];
  const unsigned short* ap = As + (wv * 16 + col) * 264 + 4 * grp;
#pragma unroll
  for (int kk = 0; kk < 8; kk++) {
    uint2 lo = *(const uint2*)(ap + kk * 32);
    uint2 hi = *(const uint2*)(ap + kk * 32 + 16);
    union { uint4 u; short8 s; } x;
    x.u.x = lo.x; x.u.y = lo.y; x.u.z = hi.x; x.u.w = hi.y;
    af[kk] = x.s;
  }
  f32x4 acc0 = {0.f, 0.f, 0.f, 0.f}, acc1 = {0.f, 0.f, 0.f, 0.f};
#pragma unroll
  for (int kk = 0; kk < 8; kk++) {
    union { uint4 u; short8 s; } b0, b1;
    b0.u = awB[(kk * 2 + 0) * 64 + l];
    b1.u = awB[(kk * 2 + 1) * 64 + l];
    acc0 = __builtin_amdgcn_mfma_f32_16x16x32_bf16(af[kk], b0.s, acc0, 0, 0, 0);
    acc1 = __builtin_amdgcn_mfma_f32_16x16x32_bf16(af[kk], b1.s, acc1, 0, 0, 0);
  }

  // row softmax over 24 cols; C/D map: col = l&15 (and +16), row = 4*grp + r
  const int n0 = col, n1 = 16 + col;
  const bool v16 = (n1 < NPT);
  const float ab0 = ab[n0];
  const float ab1 = v16 ? ab[n1] : 0.f;
#pragma unroll
  for (int r = 0; r < 4; r++) {
    float v0 = acc0[r] + ab0;
    float v1 = v16 ? (acc1[r] + ab1) : -3.4e38f;
    float m = fmaxf(v0, v1);
#pragma unroll
    for (int off = 1; off < 16; off <<= 1) m = fmaxf(m, __shfl_xor(m, off, 64));
    float e0 = __expf(v0 - m);
    float e1 = v16 ? __expf(v1 - m) : 0.f;
    float s = e0 + e1;
#pragma unroll
    for (int off = 1; off < 16; off <<= 1) s += __shfl_xor(s, off, 64);
    int qq = q0 + wv * 16 + 4 * grp + r;
    if (qq < NQ) {
      Wgt[qq * NPT + n0] = e0 / s;
      if (v16) Wgt[qq * NPT + n1] = e1 / s;
    }
  }
}

// ---------------------------------------------------------------------------
// k_main: one WAVE per query. Load softmax weight, project 24 points,
// ballot-compact valid taps, gather bf16 features, write Abf (bf16).
// ---------------------------------------------------------------------------
__global__ __launch_bounds__(256) void k_main(const unsigned short* __restrict__ featT,
                                              const float* __restrict__ l2i,
                                              const float* __restrict__ Wgt,
                                              unsigned short* __restrict__ A) {
  const int wv   = threadIdx.x >> 6;
  const int lane = threadIdx.x & 63;
  const int q    = blockIdx.x * 4 + wv;

  __shared__ float Lm[NCAM * 16];
  __shared__ int   offW[4][96];
  __shared__ float wW[4][96];

  if (threadIdx.x < NCAM * 16) Lm[threadIdx.x] = l2i[threadIdx.x];

  float sw = (lane < NPT) ? Wgt[q * NPT + lane] : 0.f;

  __syncthreads();  // Lm ready

  bool valid = false;
  int o0 = 0, o1 = 0, o2 = 0, o3 = 0;
  float w0 = 0.f, w1 = 0.f, w2 = 0.f, w3 = 0.f;
  if (lane < NPT) {
    int cam = lane >> 2, z = lane & 3;
    float X  = (((q % 100) + 0.5f) * 0.01f) * 102.4f - 51.2f;
    float Y  = (((q / 100) + 0.5f) * 0.01f) * 102.4f - 51.2f;
    float Zc = ((z + 0.5f) * 0.25f) * 8.f - 5.f;
    const float* Lr = Lm + cam * 16;
    float cx = Lr[0] * X + Lr[1] * Y + Lr[2]  * Zc + Lr[3];
    float cy = Lr[4] * X + Lr[5] * Y + Lr[6]  * Zc + Lr[7];
    float cd = Lr[8] * X + Lr[9] * Y + Lr[10] * Zc + Lr[11];
    float d  = fmaxf(cd, 1e-5f);
    float gx = (cx / d * (1.f / 87.f) - 0.5f) * 2.f;
    float gy = (cy / d * (1.f / 31.f) - 0.5f) * 2.f;
    valid = (cd > 1e-5f) && (gx > -1.f) && (gx < 1.f) && (gy > -1.f) && (gy < 1.f);

    float x = ((gx + 1.f) * 88.f - 1.f) * 0.5f;
    float y = ((gy + 1.f) * 32.f - 1.f) * 0.5f;
    float x0f = floorf(x), y0f = floorf(y);
    float wx1 = x - x0f, wy1 = y - y0f;
    float wx0 = 1.f - wx1, wy0 = 1.f - wy1;
    bool vx0 = (x0f >= 0.f) && (x0f < 88.f);
    bool vx1 = (x0f + 1.f >= 0.f) && (x0f + 1.f < 88.f);
    bool vy0 = (y0f >= 0.f) && (y0f < 32.f);
    bool vy1 = (y0f + 1.f >= 0.f) && (y0f + 1.f < 32.f);
    int x0 = (int)fminf(fmaxf(x0f, 0.f), 87.f);
    int x1 = (int)fminf(fmaxf(x0f + 1.f, 0.f), 87.f);
    int y0 = (int)fminf(fmaxf(y0f, 0.f), 31.f);
    int y1 = (int)fminf(fmaxf(y0f + 1.f, 0.f), 31.f);
    int cb = cam * (HFt * WFt);
    o0 = (cb + y0 * WFt + x0) * CH;
    o1 = (cb + y0 * WFt + x1) * CH;
    o2 = (cb + y1 * WFt + x0) * CH;
    o3 = (cb + y1 * WFt + x1) * CH;
    w0 = sw * wx0 * wy0 * ((vx0 && vy0) ? 1.f : 0.f);
    w1 = sw * wx1 * wy0 * ((vx1 && vy0) ? 1.f : 0.f);
    w2 = sw * wx0 * wy1 * ((vx0 && vy1) ? 1.f : 0.f);
    w3 = sw * wx1 * wy1 * ((vx1 && vy1) ? 1.f : 0.f);
  }

  unsigned long long vm = __ballot(valid);
  int nvalid = __popcll(vm);
  int pos = __popcll(vm & ((1ull << lane) - 1ull));
  if (valid) {
    int b = 4 * pos;
    offW[wv][b + 0] = o0; wW[wv][b + 0] = w0;
    offW[wv][b + 1] = o1; wW[wv][b + 1] = w1;
    offW[wv][b + 2] = o2; wW[wv][b + 2] = w2;
    offW[wv][b + 3] = o3; wW[wv][b + 3] = w3;
  }
  int nt  = 4 * nvalid;
  int ntp = (nt + 7) & ~7;
  if (lane < ntp - nt) { offW[wv][nt + lane] = 0; wW[wv][nt + lane] = 0.f; }

  float4 acc0 = {0.f, 0.f, 0.f, 0.f}, acc1 = {0.f, 0.f, 0.f, 0.f};
  const unsigned short* fb = featT + 4 * lane;
  for (int i = 0; i < ntp; i += 8) {
    int   a0 = offW[wv][i + 0], a1 = offW[wv][i + 1], a2 = offW[wv][i + 2], a3 = offW[wv][i + 3];
    int   a4 = offW[wv][i + 4], a5 = offW[wv][i + 5], a6 = offW[wv][i + 6], a7 = offW[wv][i + 7];
    float b0 = wW[wv][i + 0], b1 = wW[wv][i + 1], b2 = wW[wv][i + 2], b3 = wW[wv][i + 3];
    float b4 = wW[wv][i + 4], b5 = wW[wv][i + 5], b6 = wW[wv][i + 6], b7 = wW[wv][i + 7];
    ushort4 v0 = *(const ushort4*)(fb + a0);
    ushort4 v1 = *(const ushort4*)(fb + a1);
    ushort4 v2 = *(const ushort4*)(fb + a2);
    ushort4 v3 = *(const ushort4*)(fb + a3);
    ushort4 v4 = *(const ushort4*)(fb + a4);
    ushort4 v5 = *(const ushort4*)(fb + a5);
    ushort4 v6 = *(const ushort4*)(fb + a6);
    ushort4 v7 = *(const ushort4*)(fb + a7);
    acc0.x = fmaf(b0, bf2f(v0.x), acc0.x); acc0.y = fmaf(b0, bf2f(v0.y), acc0.y);
    acc0.z = fmaf(b0, bf2f(v0.z), acc0.z); acc0.w = fmaf(b0, bf2f(v0.w), acc0.w);
    acc1.x = fmaf(b1, bf2f(v1.x), acc1.x); acc1.y = fmaf(b1, bf2f(v1.y), acc1.y);
    acc1.z = fmaf(b1, bf2f(v1.z), acc1.z); acc1.w = fmaf(b1, bf2f(v1.w), acc1.w);
    acc0.x = fmaf(b2, bf2f(v2.x), acc0.x); acc0.y = fmaf(b2, bf2f(v2.y), acc0.y);
    acc0.z = fmaf(b2, bf2f(v2.z), acc0.z); acc0.w = fmaf(b2, bf2f(v2.w), acc0.w);
    acc1.x = fmaf(b3, bf2f(v3.x), acc1.x); acc1.y = fmaf(b3, bf2f(v3.y), acc1.y);
    acc1.z = fmaf(b3, bf2f(v3.z), acc1.z); acc1.w = fmaf(b3, bf2f(v3.w), acc1.w);
    acc0.x = fmaf(b4, bf2f(v4.x), acc0.x); acc0.y = fmaf(b4, bf2f(v4.y), acc0.y);
    acc0.z = fmaf(b4, bf2f(v4.z), acc0.z); acc0.w = fmaf(b4, bf2f(v4.w), acc0.w);
    acc1.x = fmaf(b5, bf2f(v5.x), acc1.x); acc1.y = fmaf(b5, bf2f(v5.y), acc1.y);
    acc1.z = fmaf(b5, bf2f(v5.z), acc1.z); acc1.w = fmaf(b5, bf2f(v5.w), acc1.w);
    acc0.x = fmaf(b6, bf2f(v6.x), acc0.x); acc0.y = fmaf(b6, bf2f(v6.y), acc0.y);
    acc0.z = fmaf(b6, bf2f(v6.z), acc0.z); acc0.w = fmaf(b6, bf2f(v6.w), acc0.w);
    acc1.x = fmaf(b7, bf2f(v7.x), acc1.x); acc1.y = fmaf(b7, bf2f(v7.y), acc1.y);
    acc1.z = fmaf(b7, bf2f(v7.z), acc1.z); acc1.w = fmaf(b7, bf2f(v7.w), acc1.w);
  }
  ushort4 st;
  st.x = f2bf(acc0.x + acc1.x); st.y = f2bf(acc0.y + acc1.y);
  st.z = f2bf(acc0.z + acc1.z); st.w = f2bf(acc0.w + acc1.w);
  *(ushort4*)(A + (size_t)q * CH + 4 * lane) = st;
}

// ---------------------------------------------------------------------------
// k_out_mfma (unchanged from R3): out = A @ out_w + ob + query
// ---------------------------------------------------------------------------
#define ASP 264
__global__ __launch_bounds__(256) void k_out_mfma(const unsigned short* __restrict__ A,
                                                  const float* __restrict__ query,
                                                  const unsigned short* __restrict__ Wsw,
                                                  const float* __restrict__ ob,
                                                  float* __restrict__ outp) {
  const int blk = blockIdx.x;
  const int mtile = blk >> 1, nhalf = blk & 1;
  const int m0 = mtile * 16;
  const int t = threadIdx.x, wv = t >> 6, l = t & 63;
  const int row = l & 15, grp = l >> 4;

  __shared__ unsigned short As[16 * ASP];

  {
    const uint4* src = (const uint4*)(A + (size_t)m0 * CH);
    uint4 v0 = src[t];
    uint4 v1 = src[t + 256];
    int r0 = t >> 5, c0 = t & 31;
    int g1 = t + 256; int r1 = g1 >> 5, c1 = g1 & 31;
    *(uint4*)(&As[r0 * ASP + c0 * 8]) = v0;
    *(uint4*)(&As[r1 * ASP + c1 * 8]) = v1;
  }
  __syncthreads();

  short8 af[8];
  {
    const unsigned short* ap = &As[row * ASP + 4 * grp];
#pragma unroll
    for (int kk = 0; kk < 8; kk++) {
      uint2 lo = *(const uint2*)(ap + kk * 32);
      uint2 hi = *(const uint2*)(ap + kk * 32 + 16);
      union { uint4 u; short8 s; } x;
      x.u.x = lo.x; x.u.y = lo.y; x.u.z = hi.x; x.u.w = hi.y;
      af[kk] = x.s;
    }
  }

  const int chunk = nhalf * 4 + wv;
  const uint4* wp = (const uint4*)Wsw;
  f32x4 acc0 = {0.f, 0.f, 0.f, 0.f}, acc1 = {0.f, 0.f, 0.f, 0.f};
#pragma unroll
  for (int kk = 0; kk < 8; kk++) {
    uint4 w0 = wp[((chunk * 8 + kk) * 2 + 0) * 64 + l];
    uint4 w1 = wp[((chunk * 8 + kk) * 2 + 1) * 64 + l];
    union { uint4 u; short8 s; } b0, b1;
    b0.u = w0; b1.u = w1;
    acc0 = __builtin_amdgcn_mfma_f32_16x16x32_bf16(af[kk], b0.s, acc0, 0, 0, 0);
    acc1 = __builtin_amdgcn_mfma_f32_16x16x32_bf16(af[kk], b1.s, acc1, 0, 0, 0);
  }

  const int nbase = nhalf * 128 + wv * 32;
#pragma unroll
  for (int f = 0; f < 2; f++) {
    f32x4 ac = (f == 0) ? acc0 : acc1;
    int n = nbase + 16 * f + row;
    float bias = ob[n];
#pragma unroll
    for (int r = 0; r < 4; r++) {
      int m = m0 + 4 * grp + r;
      size_t idx = (size_t)m * CH + n;
      outp[idx] = ac[r] + bias + query[idx];
    }
  }
}

// ---------------------------------------------------------------------------
extern "C" void kernel_launch(void* const* d_in, const int* in_sizes, int n_in,
                              void* d_out, int out_size, void* d_ws, size_t ws_size,
                              hipStream_t stream) {
  const float* query = (const float*)d_in[0];
  const float* img   = (const float*)d_in[1];
  const float* l2i   = (const float*)d_in[2];
  const float* aw    = (const float*)d_in[3];
  const float* ab    = (const float*)d_in[4];
  const float* ow    = (const float*)d_in[5];
  const float* ob    = (const float*)d_in[6];
  float* outp = (float*)d_out;

  char* ws = (char*)d_ws;
  unsigned short* featT = (unsigned short*)ws;                // 8,650,752 B (bf16)
  unsigned short* Abf   = (unsigned short*)(ws + 8650752);    // 5,120,000 B
  unsigned short* Wsw   = (unsigned short*)(ws + 13770752);   //   131,072 B
  float*          Wgt   = (float*)(ws + 13901824);            //   960,000 B

  k_prep<<<TRBLKS + WSWBLKS + NLB, 256, 0, stream>>>(img, query, aw, ab, ow, featT, Wsw, Wgt);
  k_main<<<NQ / 4, 256, 0, stream>>>(featT, l2i, Wgt, Abf);
  k_out_mfma<<<(NQ / 16) * 2, 256, 0, stream>>>(Abf, query, Wsw, ob, outp);
}